// Round 9
// baseline (234.479 us; speedup 1.0000x reference)
//
#include <hip/hip_runtime.h>
#include <stdint.h>

#define PRIME 1000003u
#define NORD  1000002u
#define KCH   16
#define BATCH 4
#define NPATCH 784
#define LLEN  9
#define IPMAX 9000          // |<x,y>| <= 20*50*9
#define TBLN  (2*IPMAX+1)
#define NDEC  (KCH*BATCH*NPATCH)   // 50176

// Barrett: M = floor(2^41/p) = 2199016; exact for t < 2^40 with one cond-sub.
__device__ __forceinline__ uint32_t mmul(uint32_t a, uint32_t b) {
    uint64_t t = (uint64_t)a * (uint64_t)b;
    uint32_t q = (uint32_t)((t * 2199016ull) >> 41);
    uint32_t r = (uint32_t)t - q * PRIME;
    return (r >= PRIME) ? r - PRIME : r;
}

__device__ __forceinline__ uint32_t mpow(uint32_t base, uint32_t exp) {
    uint32_t r = 1u, b = base;
    while (exp) {
        if (exp & 1u) r = mmul(r, b);
        b = mmul(b, b);
        exp >>= 1;
    }
    return r;
}

// ---------------- Kernel 1: dlog lookup table -------------------------------
// table[g^e mod p] = e for e in [-9000,9000]. Only queried entries are ever
// written (decrypted values are guaranteed g^e, |e|<=9000).
__global__ void build_table(const int* __restrict__ g_in, int* __restrict__ table) {
    int e = blockIdx.x * blockDim.x + threadIdx.x;
    if (e >= TBLN) return;
    int es = e - IPMAX;
    uint32_t exp = (es >= 0) ? (uint32_t)es : (uint32_t)(es + (int)NORD);
    table[mpow((uint32_t)g_in[0], exp)] = es;
}

// ---------------- Kernel 2: IPFE decrypt + table dlog + bias1+bn1+relu ------
// featr: [B][16][28][28] post bn1+relu. 196 blocks x 256 threads.
__global__ void __launch_bounds__(256) decrypt(
    const int* __restrict__ ct0, const int* __restrict__ cts,
    const int* __restrict__ y, const int* __restrict__ sk_y,
    const float* __restrict__ bias1,
    const float* __restrict__ bn1_g, const float* __restrict__ bn1_b,
    const float* __restrict__ bn1_m, const float* __restrict__ bn1_v,
    const int* __restrict__ table, float* __restrict__ featr) {
    int gtid = blockIdx.x * 256 + threadIdx.x;
    if (gtid >= NDEC) return;
    // 3136 = 49 full waves per k -> k is wave-uniform; force scalarization.
    int k = __builtin_amdgcn_readfirstlane(gtid / (BATCH * NPATCH));
    int r = gtid % (BATCH * NPATCH);
    int b = r / NPATCH;
    int j = r % NPATCH;

    const int* crow = cts + ((b * NPATCH) + j) * LLEN;
    const int* yrow = y + k * LLEN;

    uint32_t num_p = 1u, num_n = 1u;
#pragma unroll
    for (int i = 0; i < LLEN; i++) {
        int yi = yrow[i];                  // scalar load; uniform branch
        uint32_t c = (uint32_t)crow[i];
        if (yi > 0)       num_p = mmul(num_p, mpow(c, (uint32_t)yi));
        else if (yi < 0)  num_n = mmul(num_n, mpow(c, (uint32_t)(-yi)));
    }
    uint32_t den = mpow((uint32_t)ct0[b * NPATCH + j], (uint32_t)sk_y[k]);
    den = mmul(den, num_n);
    uint32_t val = mmul(num_p, mpow(den, PRIME - 2u));  // const exp: unrolls

    int ip = table[val];                   // guaranteed hit, |ip|<=9000

    float sc = bn1_g[k] * rsqrtf(bn1_v[k] + 1e-5f);
    float shf = (bias1[k] - bn1_m[k]) * sc + bn1_b[k];
    float v_ = fmaf((float)ip, sc * 1e-4f, shf);
    featr[((b * KCH) + k) * NPATCH + j] = fmaxf(v_, 0.0f);
}

// ---------------- Kernel 3: conv2 stage + conv3 stage, one block per sample -
// 4 blocks x 1024 threads. ALL weights staged to LDS via cooperative vector
// loads (lesson from R3/R8: never stream weights per-wave from global in a
// tiny-grid kernel). conv3_w staged in two 32-oc half-passes (union'd LDS).
// Output: s3g [B][576] (flat [64][3][3] post pool).
__global__ void __launch_bounds__(1024) conv23_k(
    const float* __restrict__ featr,
    const float* __restrict__ conv2_w, const float* __restrict__ conv2_b,
    const float* __restrict__ bn2_g, const float* __restrict__ bn2_b,
    const float* __restrict__ bn2_m, const float* __restrict__ bn2_v,
    const float* __restrict__ conv3_w, const float* __restrict__ conv3_b,
    const float* __restrict__ bn3_g, const float* __restrict__ bn3_b,
    const float* __restrict__ bn3_m, const float* __restrict__ bn3_v,
    float* __restrict__ s3g) {
    const int b = blockIdx.x;
    const int tid = threadIdx.x;

    __shared__ struct {
        float s2p[32][9][9];                       // 10.1 KB, persistent
        float s3[576];                             // 2.3 KB
        union {
            struct { float s1p[16][16][16]; float w2[4608]; } a;   // 34 KB
            struct { float w3[9216]; float co3[32][49]; } bb;      // 42.1 KB
        } u;
    } sh;                                          // 54.5 KB static

    // ---- A1: zero s1p + s2p halo, stage conv2 weights ----
    for (int i = tid; i < 4096; i += 1024) ((float*)sh.u.a.s1p)[i] = 0.0f;
    for (int i = tid; i < 2592; i += 1024) ((float*)sh.s2p)[i] = 0.0f;
    for (int i = tid; i < 4608; i += 1024) sh.u.a.w2[i] = conv2_w[i];
    __syncthreads();
    // pooled featr load (28->14) into s1p interior
    for (int i = tid; i < 16 * 196; i += 1024) {
        int ic = i / 196, pos = i % 196;
        int yy = pos / 14, xx = pos % 14;
        const float* fp = featr + ((b * 16 + ic) * 784) + (2 * yy) * 28 + 2 * xx;
        sh.u.a.s1p[ic][yy + 1][xx + 1] =
            fmaxf(fmaxf(fp[0], fp[1]), fmaxf(fp[28], fp[29]));
    }
    __syncthreads();

    // ---- A2: conv2 + bn2 + relu + pool(14->7) -> s2p interior ----
    for (int i = tid; i < 32 * 49; i += 1024) {
        int oc = i / 49, pos = i % 49;
        int ph = pos / 7, pw = pos % 7;
        const float* wb = &sh.u.a.w2[oc * 144];
        float sc = bn2_g[oc] * rsqrtf(bn2_v[oc] + 1e-5f);
        float shf = bn2_b[oc] - bn2_m[oc] * sc;
        float cb = conv2_b[oc];
        float mx = -1e30f;
#pragma unroll
        for (int dy = 0; dy < 2; dy++)
#pragma unroll
            for (int dx = 0; dx < 2; dx++) {
                int y0 = 2 * ph + dy, x0 = 2 * pw + dx;   // [0,14)
                float a0 = 0.0f, a1 = 0.0f, a2 = 0.0f;
#pragma unroll
                for (int ic = 0; ic < 16; ic++) {
                    const float* wp = wb + ic * 9;
                    const float* sp = &sh.u.a.s1p[ic][y0][x0];
                    a0 = fmaf(sp[0],  wp[0], fmaf(sp[1],  wp[1], fmaf(sp[2],  wp[2], a0)));
                    a1 = fmaf(sp[16], wp[3], fmaf(sp[17], wp[4], fmaf(sp[18], wp[5], a1)));
                    a2 = fmaf(sp[32], wp[6], fmaf(sp[33], wp[7], fmaf(sp[34], wp[8], a2)));
                }
                float v = (a0 + a1 + a2 + cb) * sc + shf;
                mx = fmaxf(mx, fmaxf(v, 0.0f));
            }
        sh.s2p[oc][ph + 1][pw + 1] = mx;
    }
    __syncthreads();   // s1p/w2 dead after this; u.bb may be written

    // ---- B: conv3 + bn3 + relu + pool(7->3) in two 32-oc halves ----
#pragma unroll
    for (int half = 0; half < 2; half++) {
        for (int i = tid; i < 9216; i += 1024)
            sh.u.bb.w3[i] = conv3_w[half * 9216 + i];
        __syncthreads();

        for (int i = tid; i < 32 * 49; i += 1024) {
            int ocl = i / 49, pos = i % 49;
            int oh = pos / 7, ow = pos % 7;
            int oc = half * 32 + ocl;
            const float* wb = &sh.u.bb.w3[ocl * 288];
            float a0 = 0.0f, a1 = 0.0f, a2 = 0.0f;
#pragma unroll
            for (int ic = 0; ic < 32; ic++) {
                const float* wp = wb + ic * 9;
                const float* sp = &sh.s2p[ic][oh][ow];
                a0 = fmaf(sp[0],  wp[0], fmaf(sp[1],  wp[1], fmaf(sp[2],  wp[2], a0)));
                a1 = fmaf(sp[9],  wp[3], fmaf(sp[10], wp[4], fmaf(sp[11], wp[5], a1)));
                a2 = fmaf(sp[18], wp[6], fmaf(sp[19], wp[7], fmaf(sp[20], wp[8], a2)));
            }
            float sc = bn3_g[oc] * rsqrtf(bn3_v[oc] + 1e-5f);
            float shf = bn3_b[oc] - bn3_m[oc] * sc;
            sh.u.bb.co3[ocl][pos] =
                fmaxf((a0 + a1 + a2 + conv3_b[oc]) * sc + shf, 0.0f);
        }
        __syncthreads();

        if (tid < 288) {                      // pool 7->3, windows {0,2,4}
            int ocl = tid / 9, pp = tid % 9;
            int oh = pp / 3, ow = pp % 3;
            const float* c0 = &sh.u.bb.co3[ocl][(2 * oh) * 7 + 2 * ow];
            sh.s3[(half * 32 + ocl) * 9 + pp] =
                fmaxf(fmaxf(c0[0], c0[1]), fmaxf(c0[7], c0[8]));
        }
        __syncthreads();                      // co3/w3 reusable next half
    }

    if (tid < 576) s3g[b * 576 + tid] = sh.s3[tid];
}

// ---------------- Kernel 4: fc1 + relu + fc2; ONE block, weight reuse -------
// 1 block x 1024 threads. Each wave owns 8 fc1 outputs; the 576-float weight
// row is loaded once into registers and reused across all 4 samples -> fc1_w
// fetched once total (295 KB) instead of once per sample.
__global__ void __launch_bounds__(1024) fc_k(
    const float* __restrict__ s3g,
    const float* __restrict__ fc1_w, const float* __restrict__ fc1_b,
    const float* __restrict__ fc2_w, const float* __restrict__ fc2_b,
    float* __restrict__ out) {
    const int tid = threadIdx.x;
    const int wid = tid >> 6, lane = tid & 63;
    __shared__ float s3[BATCH][576];
    __shared__ float h[BATCH][128];

    for (int i = tid; i < BATCH * 576; i += 1024)
        ((float*)s3)[i] = s3g[i];
    __syncthreads();

#pragma unroll
    for (int oo = 0; oo < 8; oo++) {
        int o = wid * 8 + oo;
        const float* w = fc1_w + o * 576;
        float wv[9];
#pragma unroll
        for (int jj = 0; jj < 9; jj++) wv[jj] = w[jj * 64 + lane];  // coalesced
        float bias = fc1_b[o];
#pragma unroll
        for (int s = 0; s < BATCH; s++) {
            float acc = 0.0f;
#pragma unroll
            for (int jj = 0; jj < 9; jj++)
                acc = fmaf(s3[s][jj * 64 + lane], wv[jj], acc);
#pragma unroll
            for (int off = 32; off; off >>= 1) acc += __shfl_down(acc, off);
            if (lane == 0) h[s][o] = fmaxf(acc + bias, 0.0f);
        }
    }
    __syncthreads();

    if (wid < 10) {
        const float* w = fc2_w + wid * 128;
        float w0 = w[lane], w1 = w[64 + lane];
        float bias = fc2_b[wid];
#pragma unroll
        for (int s = 0; s < BATCH; s++) {
            float acc = fmaf(h[s][lane], w0, 0.0f);
            acc = fmaf(h[s][64 + lane], w1, acc);
#pragma unroll
            for (int off = 32; off; off >>= 1) acc += __shfl_down(acc, off);
            if (lane == 0) out[s * 10 + wid] = acc + bias;
        }
    }
}

extern "C" void kernel_launch(void* const* d_in, const int* in_sizes, int n_in,
                              void* d_out, int out_size, void* d_ws, size_t ws_size,
                              hipStream_t stream) {
    const int*   ct0    = (const int*)d_in[0];
    const int*   cts    = (const int*)d_in[1];
    const int*   y      = (const int*)d_in[2];
    const int*   sk_y   = (const int*)d_in[3];
    const float* bias1  = (const float*)d_in[4];
    const float* bn1_g  = (const float*)d_in[5];
    const float* bn1_b  = (const float*)d_in[6];
    const float* bn1_m  = (const float*)d_in[7];
    const float* bn1_v  = (const float*)d_in[8];
    const float* conv2_w = (const float*)d_in[9];
    const float* conv2_b = (const float*)d_in[10];
    const float* bn2_g  = (const float*)d_in[11];
    const float* bn2_b  = (const float*)d_in[12];
    const float* bn2_m  = (const float*)d_in[13];
    const float* bn2_v  = (const float*)d_in[14];
    const float* conv3_w = (const float*)d_in[15];
    const float* conv3_b = (const float*)d_in[16];
    const float* bn3_g  = (const float*)d_in[17];
    const float* bn3_b  = (const float*)d_in[18];
    const float* bn3_m  = (const float*)d_in[19];
    const float* bn3_v  = (const float*)d_in[20];
    const float* fc1_w  = (const float*)d_in[21];
    const float* fc1_b  = (const float*)d_in[22];
    const float* fc2_w  = (const float*)d_in[23];
    const float* fc2_b  = (const float*)d_in[24];
    const int*   g_in   = (const int*)d_in[25];
    float* out = (float*)d_out;

    // Workspace layout (bytes):
    //   [0,        4000256)  int32 dlog table (p entries)
    //   [4000256,  4200960)  float featr [4][16][28][28]
    //   [4200960,  4210176)  float s3g   [4][576]
    char* ws = (char*)d_ws;
    int*   table = (int*)ws;
    float* featr = (float*)(ws + 4000256);
    float* s3g   = (float*)(ws + 4200960);

    build_table<<<(TBLN + 255) / 256, 256, 0, stream>>>(g_in, table);

    decrypt<<<NDEC / 256, 256, 0, stream>>>(
        ct0, cts, y, sk_y, bias1, bn1_g, bn1_b, bn1_m, bn1_v, table, featr);

    conv23_k<<<BATCH, 1024, 0, stream>>>(
        featr, conv2_w, conv2_b, bn2_g, bn2_b, bn2_m, bn2_v,
        conv3_w, conv3_b, bn3_g, bn3_b, bn3_m, bn3_v, s3g);

    fc_k<<<1, 1024, 0, stream>>>(s3g, fc1_w, fc1_b, fc2_w, fc2_b, out);
}

// Round 10
// 139.723 us; speedup vs baseline: 1.6782x; 1.6782x over previous
//
#include <hip/hip_runtime.h>
#include <stdint.h>

#define PRIME 1000003u
#define NORD  1000002u
#define KCH   16
#define BATCH 4
#define NPATCH 784
#define LLEN  9
#define IPMAX 9000          // |<x,y>| <= 20*50*9
#define TBLN  (2*IPMAX+1)
#define NDEC  (KCH*BATCH*NPATCH)   // 50176

// Barrett: M = floor(2^41/p) = 2199016; exact for t < 2^40 with one cond-sub.
__device__ __forceinline__ uint32_t mmul(uint32_t a, uint32_t b) {
    uint64_t t = (uint64_t)a * (uint64_t)b;
    uint32_t q = (uint32_t)((t * 2199016ull) >> 41);
    uint32_t r = (uint32_t)t - q * PRIME;
    return (r >= PRIME) ? r - PRIME : r;
}

__device__ __forceinline__ uint32_t mpow(uint32_t base, uint32_t exp) {
    uint32_t r = 1u, b = base;
    while (exp) {
        if (exp & 1u) r = mmul(r, b);
        b = mmul(b, b);
        exp >>= 1;
    }
    return r;
}

// ---------------- Kernel 1: dlog lookup table (int16) -----------------------
// table[g^e mod p] = e for e in [-9000,9000]; |e|<=9000 fits int16. Only
// queried entries are ever written (decrypted values are guaranteed g^e).
__global__ void build_table(const int* __restrict__ g_in, int16_t* __restrict__ table) {
    int e = blockIdx.x * blockDim.x + threadIdx.x;
    if (e >= TBLN) return;
    int es = e - IPMAX;
    uint32_t exp = (es >= 0) ? (uint32_t)es : (uint32_t)(es + (int)NORD);
    table[mpow((uint32_t)g_in[0], exp)] = (int16_t)es;
}

// ---------------- Kernel 2: IPFE decrypt + table dlog + bias1+bn1+relu ------
// featr: [B][16][28][28] post bn1+relu. 196 blocks x 256 threads.
// Shamir simultaneous exponentiation: shared squaring chain for the 9-term
// product (12 sq + ~27 cond-mul vs ~80 mmuls for 9 independent mpows).
__global__ void __launch_bounds__(256) decrypt(
    const int* __restrict__ ct0, const int* __restrict__ cts,
    const int* __restrict__ y, const int* __restrict__ sk_y,
    const float* __restrict__ bias1,
    const float* __restrict__ bn1_g, const float* __restrict__ bn1_b,
    const float* __restrict__ bn1_m, const float* __restrict__ bn1_v,
    const int16_t* __restrict__ table, float* __restrict__ featr) {
    int gtid = blockIdx.x * 256 + threadIdx.x;
    if (gtid >= NDEC) return;
    // 3136 = 49 full waves per k -> k is wave-uniform; force scalarization.
    int k = __builtin_amdgcn_readfirstlane(gtid / (BATCH * NPATCH));
    int r = gtid % (BATCH * NPATCH);
    int b = r / NPATCH;
    int j = r % NPATCH;

    const int* crow = cts + ((b * NPATCH) + j) * LLEN;
    const int* yrow = y + k * LLEN;

    uint32_t c[LLEN];
    int yv[LLEN];
#pragma unroll
    for (int i = 0; i < LLEN; i++) {
        yv[i] = yrow[i];                  // scalar loads (k wave-uniform)
        c[i]  = (uint32_t)crow[i];        // vector loads
    }

    // Shamir: |y_i| <= 50 < 64 (6 bits). Branch conds are wave-uniform.
    uint32_t accp = 1u, accn = 1u;
#pragma unroll
    for (int bit = 5; bit >= 0; bit--) {
        accp = mmul(accp, accp);
        accn = mmul(accn, accn);
#pragma unroll
        for (int i = 0; i < LLEN; i++) {
            int yi = yv[i];
            int ay = (yi > 0) ? yi : -yi;
            if ((ay >> bit) & 1) {
                if (yi > 0) accp = mmul(accp, c[i]);
                else        accn = mmul(accn, c[i]);
            }
        }
    }

    uint32_t den = mpow((uint32_t)ct0[b * NPATCH + j], (uint32_t)sk_y[k]);
    den = mmul(den, accn);
    uint32_t val = mmul(accp, mpow(den, PRIME - 2u));  // const exp: unrolls

    int ip = (int)table[val];              // guaranteed hit, |ip|<=9000

    float sc = bn1_g[k] * rsqrtf(bn1_v[k] + 1e-5f);
    float shf = (bias1[k] - bn1_m[k]) * sc + bn1_b[k];
    float v_ = fmaf((float)ip, sc * 1e-4f, shf);
    featr[((b * KCH) + k) * NPATCH + j] = fmaxf(v_, 0.0f);
}

// ---------------- Kernel 3: pool(28->14) + conv2 + bn2 + relu + pool(14->7) -
// block = (b, oc): 128 blocks x 256 threads. s2g: [B][32][7][7]
__global__ void __launch_bounds__(256) conv2_k(
    const float* __restrict__ featr,
    const float* __restrict__ conv2_w, const float* __restrict__ conv2_b,
    const float* __restrict__ bn2_g, const float* __restrict__ bn2_b,
    const float* __restrict__ bn2_m, const float* __restrict__ bn2_v,
    float* __restrict__ s2g) {
    const int b  = blockIdx.x >> 5;
    const int oc = blockIdx.x & 31;
    const int tid = threadIdx.x;

    __shared__ float s1p[16][16][16];   // padded halo of zeros, 16 KB
    __shared__ float w[16 * 9];
    __shared__ float co[196];

    for (int i = tid; i < 16 * 16 * 16; i += 256)
        ((float*)s1p)[i] = 0.0f;
    if (tid < 144) w[tid] = conv2_w[oc * 144 + tid];
    __syncthreads();
    for (int i = tid; i < 16 * 196; i += 256) {
        int ic = i / 196, pos = i % 196;
        int yy = pos / 14, xx = pos % 14;
        const float* fp = featr + ((b * 16 + ic) * 784) + (2 * yy) * 28 + 2 * xx;
        s1p[ic][yy + 1][xx + 1] = fmaxf(fmaxf(fp[0], fp[1]), fmaxf(fp[28], fp[29]));
    }
    __syncthreads();

    if (tid < 196) {
        int oh = tid / 14, ow = tid % 14;
        float a0 = 0.0f, a1 = 0.0f, a2 = 0.0f;
#pragma unroll
        for (int ic = 0; ic < 16; ic++) {
            const float* wp = &w[ic * 9];
            const float* sp = &s1p[ic][oh][ow];
            a0 = fmaf(sp[0],  wp[0], fmaf(sp[1],  wp[1], fmaf(sp[2],  wp[2], a0)));
            a1 = fmaf(sp[16], wp[3], fmaf(sp[17], wp[4], fmaf(sp[18], wp[5], a1)));
            a2 = fmaf(sp[32], wp[6], fmaf(sp[33], wp[7], fmaf(sp[34], wp[8], a2)));
        }
        float sc = bn2_g[oc] * rsqrtf(bn2_v[oc] + 1e-5f);
        float shf = bn2_b[oc] - bn2_m[oc] * sc;
        co[tid] = fmaxf((a0 + a1 + a2 + conv2_b[oc]) * sc + shf, 0.0f);
    }
    __syncthreads();

    if (tid < 49) {
        int oh = tid / 7, ow = tid % 7;
        const float* c0 = &co[(2 * oh) * 14 + 2 * ow];
        s2g[((b * 32 + oc) * 49) + tid] =
            fmaxf(fmaxf(c0[0], c0[1]), fmaxf(c0[14], c0[15]));
    }
}

// ---------------- Kernel 4: conv3 + bn3 + relu + pool(7->3) -----------------
// block = (b, oc): 256 blocks x 64 threads. s3g: [B][576] flat [64][3][3]
__global__ void __launch_bounds__(64) conv3_k(
    const float* __restrict__ s2g,
    const float* __restrict__ conv3_w, const float* __restrict__ conv3_b,
    const float* __restrict__ bn3_g, const float* __restrict__ bn3_b,
    const float* __restrict__ bn3_m, const float* __restrict__ bn3_v,
    float* __restrict__ s3g) {
    const int b  = blockIdx.x >> 6;
    const int oc = blockIdx.x & 63;
    const int tid = threadIdx.x;

    __shared__ float s2p[32][9][9];    // padded, 10.1 KB
    __shared__ float w[32 * 9];
    __shared__ float co[49];

    for (int i = tid; i < 32 * 81; i += 64)
        ((float*)s2p)[i] = 0.0f;
    for (int i = tid; i < 288; i += 64) w[i] = conv3_w[oc * 288 + i];
    __syncthreads();
    for (int i = tid; i < 32 * 49; i += 64) {
        int ic = i / 49, pos = i % 49;
        s2p[ic][pos / 7 + 1][pos % 7 + 1] = s2g[((b * 32 + ic) * 49) + pos];
    }
    __syncthreads();

    if (tid < 49) {
        int oh = tid / 7, ow = tid % 7;
        float a0 = 0.0f, a1 = 0.0f, a2 = 0.0f;
#pragma unroll
        for (int ic = 0; ic < 32; ic++) {
            const float* wp = &w[ic * 9];
            const float* sp = &s2p[ic][oh][ow];
            a0 = fmaf(sp[0],  wp[0], fmaf(sp[1],  wp[1], fmaf(sp[2],  wp[2], a0)));
            a1 = fmaf(sp[9],  wp[3], fmaf(sp[10], wp[4], fmaf(sp[11], wp[5], a1)));
            a2 = fmaf(sp[18], wp[6], fmaf(sp[19], wp[7], fmaf(sp[20], wp[8], a2)));
        }
        float sc = bn3_g[oc] * rsqrtf(bn3_v[oc] + 1e-5f);
        float shf = bn3_b[oc] - bn3_m[oc] * sc;
        co[tid] = fmaxf((a0 + a1 + a2 + conv3_b[oc]) * sc + shf, 0.0f);
    }
    __syncthreads();

    if (tid < 9) {
        int oh = tid / 3, ow = tid % 3;
        const float* c0 = &co[(2 * oh) * 7 + 2 * ow];
        s3g[b * 576 + oc * 9 + tid] = fmaxf(fmaxf(c0[0], c0[1]), fmaxf(c0[7], c0[8]));
    }
}

// ---------------- Kernel 5: fc1 + relu + fc2, wave-coalesced ----------------
// 4 blocks x 1024 threads (16 waves: 8 fc1-outputs each; 10 waves do fc2).
__global__ void __launch_bounds__(1024) fc_k(
    const float* __restrict__ s3g,
    const float* __restrict__ fc1_w, const float* __restrict__ fc1_b,
    const float* __restrict__ fc2_w, const float* __restrict__ fc2_b,
    float* __restrict__ out) {
    const int b = blockIdx.x;
    const int tid = threadIdx.x;
    const int wid = tid >> 6, lane = tid & 63;
    __shared__ float s3[576];
    __shared__ float h[128];

    for (int i = tid; i < 576; i += 1024) s3[i] = s3g[b * 576 + i];
    __syncthreads();

#pragma unroll
    for (int oo = 0; oo < 8; oo++) {
        int o = wid * 8 + oo;
        const float* w = fc1_w + o * 576;
        float acc = 0.0f;
#pragma unroll
        for (int jj = 0; jj < 9; jj++)     // lanes across 576: coalesced
            acc = fmaf(s3[jj * 64 + lane], w[jj * 64 + lane], acc);
#pragma unroll
        for (int off = 32; off; off >>= 1) acc += __shfl_down(acc, off);
        if (lane == 0) h[o] = fmaxf(acc + fc1_b[o], 0.0f);
    }
    __syncthreads();

    if (wid < 10) {
        const float* w = fc2_w + wid * 128;
        float acc = fmaf(h[lane], w[lane], 0.0f);
        acc = fmaf(h[64 + lane], w[64 + lane], acc);
#pragma unroll
        for (int off = 32; off; off >>= 1) acc += __shfl_down(acc, off);
        if (lane == 0) out[b * 10 + wid] = acc + fc2_b[wid];
    }
}

extern "C" void kernel_launch(void* const* d_in, const int* in_sizes, int n_in,
                              void* d_out, int out_size, void* d_ws, size_t ws_size,
                              hipStream_t stream) {
    const int*   ct0    = (const int*)d_in[0];
    const int*   cts    = (const int*)d_in[1];
    const int*   y      = (const int*)d_in[2];
    const int*   sk_y   = (const int*)d_in[3];
    const float* bias1  = (const float*)d_in[4];
    const float* bn1_g  = (const float*)d_in[5];
    const float* bn1_b  = (const float*)d_in[6];
    const float* bn1_m  = (const float*)d_in[7];
    const float* bn1_v  = (const float*)d_in[8];
    const float* conv2_w = (const float*)d_in[9];
    const float* conv2_b = (const float*)d_in[10];
    const float* bn2_g  = (const float*)d_in[11];
    const float* bn2_b  = (const float*)d_in[12];
    const float* bn2_m  = (const float*)d_in[13];
    const float* bn2_v  = (const float*)d_in[14];
    const float* conv3_w = (const float*)d_in[15];
    const float* conv3_b = (const float*)d_in[16];
    const float* bn3_g  = (const float*)d_in[17];
    const float* bn3_b  = (const float*)d_in[18];
    const float* bn3_m  = (const float*)d_in[19];
    const float* bn3_v  = (const float*)d_in[20];
    const float* fc1_w  = (const float*)d_in[21];
    const float* fc1_b  = (const float*)d_in[22];
    const float* fc2_w  = (const float*)d_in[23];
    const float* fc2_b  = (const float*)d_in[24];
    const int*   g_in   = (const int*)d_in[25];
    float* out = (float*)d_out;

    // Workspace layout (bytes):
    //   [0,        2000006)  int16 dlog table (p entries)
    //   [2000128,  2200832)  float featr [4][16][28][28]
    //   [2200832,  2225920)  float s2g   [4][32][7][7]
    //   [2225920,  2235136)  float s3g   [4][576]
    char* ws = (char*)d_ws;
    int16_t* table = (int16_t*)ws;
    float* featr = (float*)(ws + 2000128);
    float* s2g   = (float*)(ws + 2200832);
    float* s3g   = (float*)(ws + 2225920);

    build_table<<<(TBLN + 255) / 256, 256, 0, stream>>>(g_in, table);

    decrypt<<<NDEC / 256, 256, 0, stream>>>(
        ct0, cts, y, sk_y, bias1, bn1_g, bn1_b, bn1_m, bn1_v, table, featr);

    conv2_k<<<BATCH * 32, 256, 0, stream>>>(
        featr, conv2_w, conv2_b, bn2_g, bn2_b, bn2_m, bn2_v, s2g);

    conv3_k<<<BATCH * 64, 64, 0, stream>>>(
        s2g, conv3_w, conv3_b, bn3_g, bn3_b, bn3_m, bn3_v, s3g);

    fc_k<<<BATCH, 1024, 0, stream>>>(s3g, fc1_w, fc1_b, fc2_w, fc2_b, out);
}